// Round 8
// baseline (314.522 us; speedup 1.0000x reference)
//
#include <hip/hip_runtime.h>
#include <float.h>
#include <math.h>

#define DIM    128
#define KCB    8192
#define BT     128               // tokens per block
#define NC     128               // codes per chunk
#define NCHUNK (KCB / NC)
#define CAP    32                // refine-candidate cap per token
#define MARGIN 0.016f            // >= 2*(stage1 err bound 5.3e-3) + key-snap slack

typedef __attribute__((ext_vector_type(8))) short bf16x8;
typedef __attribute__((ext_vector_type(4))) float f32x4;

// g_eh block-transposed bake: within chunk, 16B block (r,c) -> offset n*4096+kk*1024+lg*256+l15*16
// (r = n*16+l15, c = kk*4+lg). Every main-loop ds_read_b128 is then base+lane*16: zero conflicts.
__device__ unsigned g_eh[KCB * DIM / 2];    // 2 MB packed bf16-hi pairs
__device__ float    g_h[KCB];
__device__ unsigned g_counts[KCB];
__device__ double   g_loss;
__device__ unsigned g_done;

__device__ __forceinline__ unsigned short f2b(float x) {      // RNE fp32->bf16
    union { float f; unsigned u; } v; v.f = x;
    unsigned r = v.u + 0x7fffu + ((v.u >> 16) & 1u);
    return (unsigned short)(r >> 16);
}
__device__ __forceinline__ void gll16(const void* g, void* l) {   // async global->LDS, 16B/lane
    __builtin_amdgcn_global_load_lds(
        (const __attribute__((address_space(1))) void*)g,
        (__attribute__((address_space(3))) void*)l, 16, 0, 0);
}
// order-preserving fp32->u32 flip, idx stuffed in low 13 bits (ties -> lowest idx wins at min)
__device__ __forceinline__ unsigned pkey(float sc, int c) {
    unsigned u = __float_as_uint(sc);
    u ^= (unsigned)(((int)u >> 31)) | 0x80000000u;
    return (u & ~8191u) | (unsigned)c;
}
__device__ __forceinline__ float key2sc(unsigned k) {
    unsigned u = (k & 0x80000000u) ? (k ^ 0x80000000u) : ~k;
    return __uint_as_float(u);
}

// ---------------- prep: bf16-hi split of emb (block-transposed), h_k, zero state -------------
__global__ __launch_bounds__(256) void vq_prep(const float* __restrict__ emb)
{
    const int tid = threadIdx.x;
    const int gid = blockIdx.x * 256 + tid;
    if (gid < KCB) g_counts[gid] = 0u;
    if (gid == 0)  { g_loss = 0.0; g_done = 0u; }

    const int code = (blockIdx.x << 2) + (tid >> 6);   // one wave per code
    const int lane = tid & 63;                         // word w = lane (2 dims/word)
    const float2 v = ((const float2*)emb)[code * 64 + lane];

    unsigned short h0 = f2b(v.x), h1 = f2b(v.y);
    // block-transpose dest: word = chunk*8192 + n*1024 + kk*256 + lg*64 + l15*4 + wib
    const int chunk = code >> 7, r = code & 127;
    const int n   = r >> 4,  l15r = r & 15;
    const int kk  = lane >> 4, lg = (lane >> 2) & 3, wib = lane & 3;
    const int widx = chunk * 8192 + n * 1024 + kk * 256 + lg * 64 + l15r * 4 + wib;
    g_eh[widx] = (unsigned)h0 | ((unsigned)h1 << 16);

    float s = v.x * v.x + v.y * v.y;
    #pragma unroll
    for (int o = 32; o > 0; o >>= 1) s += __shfl_down(s, o);
    if (lane == 0) g_h[code] = 0.5f * s;
}

// ---------------- main: 1-pass bf16 MFMA + margin argmin + exact fp32 refine ----------------
__global__ __launch_bounds__(1024) void vq_main(
    const float* __restrict__ z, const float* __restrict__ emb, float* __restrict__ out)
{
    __shared__ char     smem[2 * 32768];      // double-buffered eh chunk (32KB each)
    __shared__ unsigned rv[BT * 4];           // per-token per-cq slot-best keys
    __shared__ unsigned bk_sh[BT];            // per-token global best key
    __shared__ int      lcnt[BT];
    __shared__ int      list[BT * CAP];
    __shared__ int      idx_sh[BT];
    __shared__ double   wred[16];
    __shared__ int      done_sh;

    const int tid  = threadIdx.x;
    const int lane = tid & 63;
    const int wid  = tid >> 6;                // 16 waves
    const int tq   = wid >> 2;                // token group (32 tokens)
    const int cq   = wid & 3;                 // code quarter (32 codes/chunk)
    const int l15  = lane & 15;
    const int lg   = lane >> 4;
    const long t0  = (long)blockIdx.x * BT;

    // ---- A fragments: 32 z-rows, bf16-hi only ----
    bf16x8 ah[2][4];
    #pragma unroll
    for (int m = 0; m < 2; ++m) {
        const long trow = t0 + tq * 32 + m * 16 + l15;
        #pragma unroll
        for (int kk = 0; kk < 4; ++kk) {
            const float4* zp = (const float4*)(z + trow * DIM + kk * 32 + lg * 8);
            float4 v0 = zp[0], v1 = zp[1];
            float xs[8] = {v0.x, v0.y, v0.z, v0.w, v1.x, v1.y, v1.z, v1.w};
            #pragma unroll
            for (int j = 0; j < 8; ++j) ah[m][kk][j] = (short)f2b(xs[j]);
        }
    }

    // conflict-free read base: every ds_read_b128 is a linear 1024B span (addr = base + lane*16)
    const int rbase = cq * 8192 + (lane << 4);

    unsigned b0[2][4], b1[2][4];              // 2-deep packed candidate keys per slot
    #pragma unroll
    for (int m = 0; m < 2; ++m)
        #pragma unroll
        for (int r = 0; r < 4; ++r) { b0[m][r] = 0xFFFFFFFFu; b1[m][r] = 0xFFFFFFFFu; }

    // prologue: stage chunk 0 (1024 thr x 16B = 16KB per round)
    {
        const int o = tid * 16;
        gll16((const char*)g_eh + o, smem + o);
        gll16((const char*)g_eh + 16384 + o, smem + 16384 + o);
    }
    __syncthreads();

    for (int ch = 0; ch < NCHUNK; ++ch) {
        const int cur = ch & 1;
        if (ch + 1 < NCHUNK) {
            const int  o  = tid * 16;
            const long go = (long)(ch + 1) * 32768;
            char* ldst = smem + (cur ^ 1) * 32768;
            gll16((const char*)g_eh + go + o, ldst + o);
            gll16((const char*)g_eh + go + 16384 + o, ldst + 16384 + o);
        }

        const char* base = smem + cur * 32768 + rbase;
        const int   c0   = ch * NC + cq * 32 + l15;
        const float hv0  = g_h[c0];
        const float hv1  = g_h[c0 + 16];

        #pragma unroll
        for (int n = 0; n < 2; ++n) {
            bf16x8 bh[4];
            #pragma unroll
            for (int kk = 0; kk < 4; ++kk)
                bh[kk] = *(const bf16x8*)(base + n * 4096 + kk * 1024);
            f32x4 acc[2];
            #pragma unroll
            for (int m = 0; m < 2; ++m) acc[m] = (f32x4){0.f, 0.f, 0.f, 0.f};
            #pragma unroll
            for (int kk = 0; kk < 4; ++kk)
                #pragma unroll
                for (int m = 0; m < 2; ++m)
                    acc[m] = __builtin_amdgcn_mfma_f32_16x16x32_bf16(ah[m][kk], bh[kk], acc[m], 0, 0, 0);

            const float hvn = n ? hv1 : hv0;
            const int   c   = c0 + n * 16;
            #pragma unroll
            for (int m = 0; m < 2; ++m)
                #pragma unroll
                for (int r = 0; r < 4; ++r) {
                    unsigned k  = pkey(hvn - acc[m][r], c);
                    unsigned mx = max(b0[m][r], k);
                    b0[m][r] = min(b0[m][r], k);
                    b1[m][r] = min(b1[m][r], mx);
                }
        }
        __syncthreads();
    }

    // ---- global best key per token ----
    #pragma unroll
    for (int m = 0; m < 2; ++m)
        #pragma unroll
        for (int r = 0; r < 4; ++r) {
            unsigned k = b0[m][r];
            #pragma unroll
            for (int o = 1; o < 16; o <<= 1) k = min(k, (unsigned)__shfl_xor((int)k, o));
            if (l15 == 0) rv[(tq * 32 + m * 16 + lg * 4 + r) * 4 + cq] = k;
        }
    __syncthreads();
    if (tid < BT) {
        unsigned k = min(min(rv[tid * 4], rv[tid * 4 + 1]), min(rv[tid * 4 + 2], rv[tid * 4 + 3]));
        bk_sh[tid] = k;
        lcnt[tid]  = 0;
    }
    __syncthreads();

    // ---- collect candidates within margin of best ----
    #pragma unroll
    for (int m = 0; m < 2; ++m)
        #pragma unroll
        for (int r = 0; r < 4; ++r) {
            const int   t  = tq * 32 + m * 16 + lg * 4 + r;
            const float th = key2sc(bk_sh[t]) + MARGIN;
            if (key2sc(b0[m][r]) <= th) {
                int p = atomicAdd(&lcnt[t], 1);
                if (p < CAP) list[t * CAP + p] = (int)(b0[m][r] & 8191u);
            }
            if (key2sc(b1[m][r]) <= th) {
                int p = atomicAdd(&lcnt[t], 1);
                if (p < CAP) list[t * CAP + p] = (int)(b1[m][r] & 8191u);
            }
        }
    __syncthreads();

    // ---- exact fp32 refine: 8 tokens/wave, 8 lanes/token ----
    {
        const int t  = wid * 8 + (lane >> 3);
        const int li = lane & 7;
        const int cnt = min(lcnt[t], CAP);
        const float4* zt = (const float4*)(z + (t0 + t) * DIM) + li * 4;
        float4 zr0 = zt[0], zr1 = zt[1], zr2 = zt[2], zr3 = zt[3];
        float bsc = FLT_MAX; int bidx = KCB;
        for (int j = 0; j < cnt; ++j) {
            const int c = list[t * CAP + j];
            const float4* ec = (const float4*)(emb + (size_t)c * DIM) + li * 4;
            float4 e0 = ec[0], e1 = ec[1], e2 = ec[2], e3 = ec[3];
            float s = zr0.x*e0.x + zr0.y*e0.y + zr0.z*e0.z + zr0.w*e0.w
                    + zr1.x*e1.x + zr1.y*e1.y + zr1.z*e1.z + zr1.w*e1.w
                    + zr2.x*e2.x + zr2.y*e2.y + zr2.z*e2.z + zr2.w*e2.w
                    + zr3.x*e3.x + zr3.y*e3.y + zr3.z*e3.z + zr3.w*e3.w;
            #pragma unroll
            for (int o = 1; o < 8; o <<= 1) s += __shfl_xor(s, o);
            float sc = g_h[c] - s;
            if (sc < bsc || (sc == bsc && c < bidx)) { bsc = sc; bidx = c; }
        }
        if (li == 0) {
            idx_sh[t] = bidx;
            atomicAdd(&g_counts[bidx], 1u);
        }
    }
    __syncthreads();

    // ---- epilogue: gather e[idx], out = z + (zq - z), loss partial ----
    float lsum = 0.f;
    {
        const float4* zf4 = (const float4*)(z + t0 * DIM);
        const float4* ef4 = (const float4*)emb;
        float4*       of4 = (float4*)(out + t0 * DIM);
        #pragma unroll
        for (int r = 0; r < 4; ++r) {
            int f = r * 1024 + tid;
            int t = f >> 5, dw = f & 31;
            int ci = idx_sh[t];
            float4 e4 = ef4[(size_t)ci * 32 + dw];
            float4 z4 = zf4[f];
            float dx = e4.x - z4.x, dy = e4.y - z4.y;
            float dz = e4.z - z4.z, dw2 = e4.w - z4.w;
            lsum += dx * dx + dy * dy + dz * dz + dw2 * dw2;
            float4 o;
            o.x = z4.x + dx; o.y = z4.y + dy; o.z = z4.z + dz; o.w = z4.w + dw2;
            of4[f] = o;
        }
    }
    #pragma unroll
    for (int o = 32; o > 0; o >>= 1) lsum += __shfl_down(lsum, o);
    if (lane == 0) wred[wid] = (double)lsum;
    __syncthreads();
    if (tid == 0) {
        double s = 0.0;
        #pragma unroll
        for (int w = 0; w < 16; ++w) s += wred[w];
        atomicAdd(&g_loss, s);
    }

    // ---- last block: perplexity + commit loss ----
    __threadfence();
    if (tid == 0) done_sh = (atomicAdd(&g_done, 1u) == gridDim.x - 1) ? 1 : 0;
    __syncthreads();
    if (done_sh) {
        const int ntok    = (int)gridDim.x * BT;
        const int n_elems = ntok * DIM;
        double s = 0.0;
        for (int i = tid; i < KCB; i += 1024) {
            unsigned cnt = atomicAdd(&g_counts[i], 0u);
            float em = (float)cnt / (float)ntok;
            s += (double)(em * logf(em + 1e-8f));
        }
        #pragma unroll
        for (int o = 32; o > 0; o >>= 1) s += __shfl_down(s, o);
        if (lane == 0) wred[wid] = s;
        __syncthreads();
        if (tid == 0) {
            double tot = 0.0;
            #pragma unroll
            for (int w = 0; w < 16; ++w) tot += wred[w];
            double L = atomicAdd(&g_loss, 0.0);
            out[(size_t)n_elems]     = (float)(1.25 * L / (double)n_elems);
            out[(size_t)n_elems + 1] = expf((float)(-tot));
        }
    }
}

extern "C" void kernel_launch(void* const* d_in, const int* in_sizes, int n_in,
                              void* d_out, int out_size, void* d_ws, size_t ws_size,
                              hipStream_t stream)
{
    const float* z   = (const float*)d_in[0];
    const float* emb = (const float*)d_in[1];
    float* out = (float*)d_out;

    const int n_elems = in_sizes[0];        // 4194304
    const int ntok    = n_elems / DIM;      // 32768

    vq_prep<<<dim3(KCB / 4),   256,  0, stream>>>(emb);
    vq_main<<<dim3(ntok / BT), 1024, 0, stream>>>(z, emb, out);
}

// Round 9
// 292.922 us; speedup vs baseline: 1.0737x; 1.0737x over previous
//
#include <hip/hip_runtime.h>
#include <float.h>
#include <math.h>

#define DIM    128
#define KCB    8192
#define BT     128               // tokens per block
#define NC     128               // codes per chunk
#define NCHUNK (KCB / NC)
#define CAP    32                // refine-candidate cap per token
#define MARGIN 0.016f            // >= 2*(stage1 err bound 5.3e-3) + key-snap slack

typedef __attribute__((ext_vector_type(8))) short bf16x8;
typedef __attribute__((ext_vector_type(4))) float f32x4;

// g_eh block-transposed bake: 16B block (r,c) of chunk -> byte (r>>4)*4096 + c*... such that a
// wave's MFMA B-fragment j (j=0..7) for code-quarter cq is the contiguous 1KB span
//   g_eh + ch*32768 + cq*8192 + j*1024 + lane*16      (fully coalesced; L1/L2-resident)
__device__ unsigned g_eh[KCB * DIM / 2];    // 2 MB packed bf16-hi pairs
__device__ float    g_h[KCB];
__device__ unsigned g_counts[KCB];
__device__ double   g_loss;
__device__ unsigned g_done;

__device__ __forceinline__ unsigned short f2b(float x) {      // RNE fp32->bf16
    union { float f; unsigned u; } v; v.f = x;
    unsigned r = v.u + 0x7fffu + ((v.u >> 16) & 1u);
    return (unsigned short)(r >> 16);
}
// order-preserving fp32->u32 flip, idx stuffed in low 13 bits (ties -> lowest idx wins at min)
__device__ __forceinline__ unsigned pkey(float sc, int c) {
    unsigned u = __float_as_uint(sc);
    u ^= (unsigned)(((int)u >> 31)) | 0x80000000u;
    return (u & ~8191u) | (unsigned)c;
}
__device__ __forceinline__ float key2sc(unsigned k) {
    unsigned u = (k & 0x80000000u) ? (k ^ 0x80000000u) : ~k;
    return __uint_as_float(u);
}

// ---------------- prep: bf16-hi split of emb (block-transposed), h_k, zero state -------------
__global__ __launch_bounds__(256) void vq_prep(const float* __restrict__ emb)
{
    const int tid = threadIdx.x;
    const int gid = blockIdx.x * 256 + tid;
    if (gid < KCB) g_counts[gid] = 0u;
    if (gid == 0)  { g_loss = 0.0; g_done = 0u; }

    const int code = (blockIdx.x << 2) + (tid >> 6);   // one wave per code
    const int lane = tid & 63;                         // word w = lane (2 dims/word)
    const float2 v = ((const float2*)emb)[code * 64 + lane];

    unsigned short h0 = f2b(v.x), h1 = f2b(v.y);
    // dest word = chunk*8192 + n*1024 + kk*256 + lg*64 + l15*4 + wib  (r=n*16+l15, c=kk*4+lg)
    const int chunk = code >> 7, r = code & 127;
    const int n   = r >> 4,  l15r = r & 15;
    const int kk  = lane >> 4, lg = (lane >> 2) & 3, wib = lane & 3;
    const int widx = chunk * 8192 + n * 1024 + kk * 256 + lg * 64 + l15r * 4 + wib;
    g_eh[widx] = (unsigned)h0 | ((unsigned)h1 << 16);

    float s = v.x * v.x + v.y * v.y;
    #pragma unroll
    for (int o = 32; o > 0; o >>= 1) s += __shfl_down(s, o);
    if (lane == 0) g_h[code] = 0.5f * s;
}

// ---------------- main: barrier-free 1-pass bf16 MFMA + margin argmin + fp32 refine ---------
__global__ __launch_bounds__(1024) void vq_main(
    const float* __restrict__ z, const float* __restrict__ emb, float* __restrict__ out)
{
    __shared__ unsigned rv[BT * 4];           // per-token per-cq slot-best keys
    __shared__ unsigned bk_sh[BT];            // per-token global best key
    __shared__ int      lcnt[BT];
    __shared__ int      list[BT * CAP];
    __shared__ int      idx_sh[BT];
    __shared__ double   wred[16];
    __shared__ int      done_sh;

    const int tid  = threadIdx.x;
    const int lane = tid & 63;
    const int wid  = tid >> 6;                // 16 waves
    const int tq   = wid >> 2;                // token group (32 tokens)
    const int cq   = wid & 3;                 // code quarter (32 codes/chunk)
    const int l15  = lane & 15;
    const int lg   = lane >> 4;
    const long t0  = (long)blockIdx.x * BT;

    // ---- A fragments: 32 z-rows, bf16-hi only ----
    bf16x8 ah[2][4];
    #pragma unroll
    for (int m = 0; m < 2; ++m) {
        const long trow = t0 + tq * 32 + m * 16 + l15;
        #pragma unroll
        for (int kk = 0; kk < 4; ++kk) {
            const float4* zp = (const float4*)(z + trow * DIM + kk * 32 + lg * 8);
            float4 v0 = zp[0], v1 = zp[1];
            float xs[8] = {v0.x, v0.y, v0.z, v0.w, v1.x, v1.y, v1.z, v1.w};
            #pragma unroll
            for (int j = 0; j < 8; ++j) ah[m][kk][j] = (short)f2b(xs[j]);
        }
    }

    unsigned b0[2][4], b1[2][4];              // 2-deep packed candidate keys per slot
    #pragma unroll
    for (int m = 0; m < 2; ++m)
        #pragma unroll
        for (int r = 0; r < 4; ++r) { b0[m][r] = 0xFFFFFFFFu; b1[m][r] = 0xFFFFFFFFu; }

    // ---- barrier-free main loop: B-fragments straight from L1/L2, 2-stage reg pipeline ----
    const char* gbase = (const char*)g_eh + cq * 8192 + (lane << 4);

    bf16x8 bcur[8], bnxt[8];
    #pragma unroll
    for (int j = 0; j < 8; ++j) bcur[j] = *(const bf16x8*)(gbase + j * 1024);

    for (int ch = 0; ch < NCHUNK; ++ch) {
        if (ch + 1 < NCHUNK) {                // prefetch next chunk's fragments into regs
            const char* gn = gbase + (long)(ch + 1) * 32768;
            #pragma unroll
            for (int j = 0; j < 8; ++j) bnxt[j] = *(const bf16x8*)(gn + j * 1024);
        }

        const int   c0  = ch * NC + cq * 32 + l15;
        const float hv0 = g_h[c0];
        const float hv1 = g_h[c0 + 16];

        #pragma unroll
        for (int n = 0; n < 2; ++n) {
            f32x4 acc[2];
            #pragma unroll
            for (int m = 0; m < 2; ++m) acc[m] = (f32x4){0.f, 0.f, 0.f, 0.f};
            #pragma unroll
            for (int kk = 0; kk < 4; ++kk)
                #pragma unroll
                for (int m = 0; m < 2; ++m)
                    acc[m] = __builtin_amdgcn_mfma_f32_16x16x32_bf16(ah[m][kk], bcur[n * 4 + kk], acc[m], 0, 0, 0);

            const float hvn = n ? hv1 : hv0;
            const int   c   = c0 + n * 16;
            #pragma unroll
            for (int m = 0; m < 2; ++m)
                #pragma unroll
                for (int r = 0; r < 4; ++r) {
                    unsigned k  = pkey(hvn - acc[m][r], c);
                    unsigned mx = max(b0[m][r], k);
                    b0[m][r] = min(b0[m][r], k);
                    b1[m][r] = min(b1[m][r], mx);
                }
        }
        #pragma unroll
        for (int j = 0; j < 8; ++j) bcur[j] = bnxt[j];
    }

    // ---- global best key per token ----
    #pragma unroll
    for (int m = 0; m < 2; ++m)
        #pragma unroll
        for (int r = 0; r < 4; ++r) {
            unsigned k = b0[m][r];
            #pragma unroll
            for (int o = 1; o < 16; o <<= 1) k = min(k, (unsigned)__shfl_xor((int)k, o));
            if (l15 == 0) rv[(tq * 32 + m * 16 + lg * 4 + r) * 4 + cq] = k;
        }
    __syncthreads();
    if (tid < BT) {
        unsigned k = min(min(rv[tid * 4], rv[tid * 4 + 1]), min(rv[tid * 4 + 2], rv[tid * 4 + 3]));
        bk_sh[tid] = k;
        lcnt[tid]  = 0;
    }
    __syncthreads();

    // ---- collect candidates within margin of best ----
    #pragma unroll
    for (int m = 0; m < 2; ++m)
        #pragma unroll
        for (int r = 0; r < 4; ++r) {
            const int   t  = tq * 32 + m * 16 + lg * 4 + r;
            const float th = key2sc(bk_sh[t]) + MARGIN;
            if (key2sc(b0[m][r]) <= th) {
                int p = atomicAdd(&lcnt[t], 1);
                if (p < CAP) list[t * CAP + p] = (int)(b0[m][r] & 8191u);
            }
            if (key2sc(b1[m][r]) <= th) {
                int p = atomicAdd(&lcnt[t], 1);
                if (p < CAP) list[t * CAP + p] = (int)(b1[m][r] & 8191u);
            }
        }
    __syncthreads();

    // ---- exact fp32 refine: 8 tokens/wave, 8 lanes/token ----
    {
        const int t  = wid * 8 + (lane >> 3);
        const int li = lane & 7;
        const int cnt = min(lcnt[t], CAP);
        const float4* zt = (const float4*)(z + (t0 + t) * DIM) + li * 4;
        float4 zr0 = zt[0], zr1 = zt[1], zr2 = zt[2], zr3 = zt[3];
        float bsc = FLT_MAX; int bidx = KCB;
        for (int j = 0; j < cnt; ++j) {
            const int c = list[t * CAP + j];
            const float4* ec = (const float4*)(emb + (size_t)c * DIM) + li * 4;
            float4 e0 = ec[0], e1 = ec[1], e2 = ec[2], e3 = ec[3];
            float s = zr0.x*e0.x + zr0.y*e0.y + zr0.z*e0.z + zr0.w*e0.w
                    + zr1.x*e1.x + zr1.y*e1.y + zr1.z*e1.z + zr1.w*e1.w
                    + zr2.x*e2.x + zr2.y*e2.y + zr2.z*e2.z + zr2.w*e2.w
                    + zr3.x*e3.x + zr3.y*e3.y + zr3.z*e3.z + zr3.w*e3.w;
            #pragma unroll
            for (int o = 1; o < 8; o <<= 1) s += __shfl_xor(s, o);
            float sc = g_h[c] - s;
            if (sc < bsc || (sc == bsc && c < bidx)) { bsc = sc; bidx = c; }
        }
        if (li == 0) {
            idx_sh[t] = bidx;
            atomicAdd(&g_counts[bidx], 1u);
        }
    }
    __syncthreads();

    // ---- epilogue: gather e[idx], out = z + (zq - z), loss partial ----
    float lsum = 0.f;
    {
        const float4* zf4 = (const float4*)(z + t0 * DIM);
        const float4* ef4 = (const float4*)emb;
        float4*       of4 = (float4*)(out + t0 * DIM);
        #pragma unroll
        for (int r = 0; r < 4; ++r) {
            int f = r * 1024 + tid;
            int t = f >> 5, dw = f & 31;
            int ci = idx_sh[t];
            float4 e4 = ef4[(size_t)ci * 32 + dw];
            float4 z4 = zf4[f];
            float dx = e4.x - z4.x, dy = e4.y - z4.y;
            float dz = e4.z - z4.z, dw2 = e4.w - z4.w;
            lsum += dx * dx + dy * dy + dz * dz + dw2 * dw2;
            float4 o;
            o.x = z4.x + dx; o.y = z4.y + dy; o.z = z4.z + dz; o.w = z4.w + dw2;
            of4[f] = o;
        }
    }
    #pragma unroll
    for (int o = 32; o > 0; o >>= 1) lsum += __shfl_down(lsum, o);
    if (lane == 0) wred[wid] = (double)lsum;
    __syncthreads();
    if (tid == 0) {
        double s = 0.0;
        #pragma unroll
        for (int w = 0; w < 16; ++w) s += wred[w];
        atomicAdd(&g_loss, s);
    }

    // ---- last block: perplexity + commit loss ----
    __threadfence();
    if (tid == 0) done_sh = (atomicAdd(&g_done, 1u) == gridDim.x - 1) ? 1 : 0;
    __syncthreads();
    if (done_sh) {
        const int ntok    = (int)gridDim.x * BT;
        const int n_elems = ntok * DIM;
        double s = 0.0;
        for (int i = tid; i < KCB; i += 1024) {
            unsigned cnt = atomicAdd(&g_counts[i], 0u);
            float em = (float)cnt / (float)ntok;
            s += (double)(em * logf(em + 1e-8f));
        }
        #pragma unroll
        for (int o = 32; o > 0; o >>= 1) s += __shfl_down(s, o);
        if (lane == 0) wred[wid] = s;
        __syncthreads();
        if (tid == 0) {
            double tot = 0.0;
            #pragma unroll
            for (int w = 0; w < 16; ++w) tot += wred[w];
            double L = atomicAdd(&g_loss, 0.0);
            out[(size_t)n_elems]     = (float)(1.25 * L / (double)n_elems);
            out[(size_t)n_elems + 1] = expf((float)(-tot));
        }
    }
}

extern "C" void kernel_launch(void* const* d_in, const int* in_sizes, int n_in,
                              void* d_out, int out_size, void* d_ws, size_t ws_size,
                              hipStream_t stream)
{
    const float* z   = (const float*)d_in[0];
    const float* emb = (const float*)d_in[1];
    float* out = (float*)d_out;

    const int n_elems = in_sizes[0];        // 4194304
    const int ntok    = n_elems / DIM;      // 32768

    vq_prep<<<dim3(KCB / 4),   256,  0, stream>>>(emb);
    vq_main<<<dim3(ntok / BT), 1024, 0, stream>>>(z, emb, out);
}